// Round 2
// baseline (85107.715 us; speedup 1.0000x reference)
//
#include <hip/hip_runtime.h>
#include <hip/hip_bf16.h>
#include <cstdint>
#include <cstddef>

#define Bsz 512
#define Ssz 128
#define Fsz 128
#define Hsz 512
#define NTWO 1024  /* 2H */

typedef __attribute__((ext_vector_type(8))) short short8;
typedef __attribute__((ext_vector_type(4))) float f32x4;

__device__ __forceinline__ float b2f(unsigned short u){
  union { unsigned int i; float f; } v; v.i = ((unsigned int)u) << 16; return v.f;
}
__device__ __forceinline__ unsigned short f2b(float f){
  union { float f; unsigned int i; } v; v.f = f;
  unsigned int x = v.i;
  return (unsigned short)((x + 0x7fffu + ((x >> 16) & 1u)) >> 16);
}

typedef unsigned int u32;
__device__ __forceinline__ void g2l16(const void* g, void* l){
  __builtin_amdgcn_global_load_lds((const __attribute__((address_space(1))) u32*)g,
                                   (__attribute__((address_space(3))) u32*)l, 16, 0, 0);
}

// RK45 (Dormand-Prince) b-coefficients
#define RB1 0.09114583333333333f
#define RB3 0.4492362982929021f
#define RB4 0.6510416666666666f
#define RB5 (-0.3223921568627451f)
#define RB6 0.13095238095238096f

struct GArgs {
  const unsigned short* A; const unsigned short* Bt;
  int a_rs, b_rs, K, kmask, N;
  int mode, stage, wtbf;
  const float* subp;
  const float* u;
  float* p; unsigned short* t;
  unsigned short *q0,*q1,*q2,*q3,*q4;
  float* Tacc; unsigned short* Tbf;
  float* h; unsigned short* h2;
  const float* bias;
  float* GO;
  const float* dti; const float* wdt;
  unsigned short* GtOut;
};

// General GEMM: C[m,n] = sum_k A[m,k] * Bt[n, k & kmask], M = grid.x*64, N = grid.y*32.
// modes: 0 ODE stage, 1 step_p, 2 ODE finish, 3 GH, 4 GI, 5 G-precompute
__launch_bounds__(256)
__global__ void gemm_k(GArgs g){
  __shared__ __align__(16) unsigned short lA[2][64*64];
  __shared__ __align__(16) unsigned short lB[2][32*64];
  const int tid = threadIdx.x;
  const int wave = tid >> 6, lane = tid & 63;
  const int quad = lane >> 4, l16 = lane & 15;
  const int mb = blockIdx.x * 64;
  const int nb = blockIdx.y * 32;
  f32x4 acc0 = {0.f,0.f,0.f,0.f}, acc1 = {0.f,0.f,0.f,0.f};

  const int r0 = tid >> 3,         c0 = (tid & 7) ^ (r0 & 7);
  const int r1 = (256 + tid) >> 3, c1 = (tid & 7) ^ (r1 & 7);

  const int am = wave*16 + l16;
  const int aoff0 = am*64 + (((quad    ) ^ (am & 7)) << 3);
  const int aoff1 = am*64 + (((4 + quad) ^ (am & 7)) << 3);
  const int bn0 = l16, bn1 = 16 + l16;
  const int boff00 = bn0*64 + (((quad    ) ^ (bn0 & 7)) << 3);
  const int boff01 = bn0*64 + (((4 + quad) ^ (bn0 & 7)) << 3);
  const int boff10 = bn1*64 + (((quad    ) ^ (bn1 & 7)) << 3);
  const int boff11 = bn1*64 + (((4 + quad) ^ (bn1 & 7)) << 3);

  const int nkb = g.K >> 6;
  {
    g2l16(g.A  + (size_t)(mb + r0) * g.a_rs + ((c0 << 3)),             &lA[0][tid << 3]);
    g2l16(g.A  + (size_t)(mb + r1) * g.a_rs + ((c1 << 3)),             &lA[0][(256 + tid) << 3]);
    g2l16(g.Bt + (size_t)(nb + r0) * g.b_rs + (((c0 << 3)) & g.kmask), &lB[0][tid << 3]);
  }
  __syncthreads();
  for (int kb = 0; kb < nkb; ++kb){
    int buf = kb & 1;
    if (kb + 1 < nkb){
      int k0 = (kb + 1) << 6, nbuf = buf ^ 1;
      g2l16(g.A  + (size_t)(mb + r0) * g.a_rs + (k0 + (c0 << 3)),             &lA[nbuf][tid << 3]);
      g2l16(g.A  + (size_t)(mb + r1) * g.a_rs + (k0 + (c1 << 3)),             &lA[nbuf][(256 + tid) << 3]);
      g2l16(g.Bt + (size_t)(nb + r0) * g.b_rs + ((k0 + (c0 << 3)) & g.kmask), &lB[nbuf][tid << 3]);
    }
    short8 a0  = *(const short8*)&lA[buf][aoff0];
    short8 a1  = *(const short8*)&lA[buf][aoff1];
    short8 b00 = *(const short8*)&lB[buf][boff00];
    short8 b01 = *(const short8*)&lB[buf][boff01];
    short8 b10 = *(const short8*)&lB[buf][boff10];
    short8 b11 = *(const short8*)&lB[buf][boff11];
    acc0 = __builtin_amdgcn_mfma_f32_16x16x32_bf16(a0, b00, acc0, 0, 0, 0);
    acc0 = __builtin_amdgcn_mfma_f32_16x16x32_bf16(a1, b01, acc0, 0, 0, 0);
    acc1 = __builtin_amdgcn_mfma_f32_16x16x32_bf16(a0, b10, acc1, 0, 0, 0);
    acc1 = __builtin_amdgcn_mfma_f32_16x16x32_bf16(a1, b11, acc1, 0, 0, 0);
    __syncthreads();
  }

  float subv = g.subp ? *g.subp : 0.f;
  #pragma unroll
  for (int cb = 0; cb < 2; ++cb){
    f32x4 a = cb ? acc1 : acc0;
    int n = nb + cb*16 + l16;
    #pragma unroll
    for (int r = 0; r < 4; ++r){
      int m = mb + wave*16 + quad*4 + r;
      float v = a[r];
      if (g.mode == 0){
        int idx = m*NTWO + n;
        float qv = v + g.u[n];
        float zs;
        int st = g.stage;
        if (st == 1){ g.q0[idx] = f2b(qv); zs = 0.2f*qv; }
        else if (st == 2){ g.q1[idx] = f2b(qv);
          zs = 0.075f*b2f(g.q0[idx]) + 0.225f*qv; }
        else if (st == 3){ g.q2[idx] = f2b(qv);
          zs = (44.f/45.f)*b2f(g.q0[idx]) + (-56.f/15.f)*b2f(g.q1[idx]) + (32.f/9.f)*qv; }
        else if (st == 4){ g.q3[idx] = f2b(qv);
          zs = 2.9525986892242035f*b2f(g.q0[idx]) + (-11.595793324188385f)*b2f(g.q1[idx])
             + 9.822892851699436f*b2f(g.q2[idx]) + (-0.2908093278463649f)*qv; }
        else if (st == 5){ g.q4[idx] = f2b(qv);
          zs = 2.8462752525252526f*b2f(g.q0[idx]) + (-10.757575757575758f)*b2f(g.q1[idx])
             + 8.906422717743473f*b2f(g.q2[idx]) + 0.2784090909090909f*b2f(g.q3[idx])
             + (-0.2735313036020583f)*qv; }
        else {
          zs = RB1*b2f(g.q0[idx]) + RB3*b2f(g.q2[idx]) + RB4*b2f(g.q3[idx])
             + RB5*b2f(g.q4[idx]) + RB6*qv;
        }
        if (st < 6){
          float z = g.p[idx] + subv*zs;
          float tv = tanhf(z);
          g.t[idx] = f2b(tv);
          if (st >= 2){
            const float bnext[6] = {0.f, 0.f, RB3, RB4, RB5, RB6};
            float ta = g.Tacc[idx] + subv*bnext[st]*tv;
            g.Tacc[idx] = ta;
            if (g.wtbf) g.Tbf[idx] = f2b(ta);
          }
        } else {
          float pn = g.p[idx] + subv*zs;
          g.p[idx] = pn;
          float tv = tanhf(pn);
          g.t[idx] = f2b(tv);
          g.Tacc[idx] = g.Tacc[idx] + subv*RB1*tv;
        }
      } else if (g.mode == 1){
        int idx = m*NTWO + n;
        float pv = v + g.bias[n];
        g.p[idx] = pv;
        float tv = tanhf(pv);
        g.t[idx] = f2b(tv);
        g.Tacc[idx] = subv*RB1*tv;
      } else if (g.mode == 2){
        int ih = m*Hsz + n;
        float hv = g.h[ih] + v + 8.f*subv*g.bias[n];
        g.h[ih] = hv;
        unsigned short hi = f2b(hv);
        g.h2[m*NTWO + n] = hi;
        g.h2[m*NTWO + Hsz + n] = f2b(hv - b2f(hi));
      } else if (g.mode == 3){
        g.GO[m*1536 + n] = v + g.bias[n];
      } else if (g.mode == 4){
        g.GO[m*1536 + n] = v + g.bias[n] + g.dti[m*Ssz]*g.wdt[n];
      } else {
        g.GtOut[m*NTWO + n] = f2b(v);
      }
    }
  }
}

__global__ void zero_k(float* h, unsigned short* h2){
  int i = blockIdx.x*256 + threadIdx.x;
  if (i < Bsz*Hsz) h[i] = 0.f;
  h2[i] = 0;
}

__global__ void tsm_k(const float* tp, float* tsm){
  int s = blockIdx.x, tid = threadIdx.x;
  __shared__ float red[8];
  float v = tp[(size_t)tid*Ssz + s] + tp[(size_t)(tid + 256)*Ssz + s];
  int wave = tid >> 6, lane = tid & 63;
  for (int o = 32; o; o >>= 1) v += __shfl_down(v, o);
  if (!lane) red[wave] = v;
  __syncthreads();
  if (!tid) tsm[s] = (red[0] + red[1] + red[2] + red[3]) * (1.f/(512.f*72.f));
}

__global__ void sub_k(const float* tsm, float* subs){
  int i = threadIdx.x;
  if (i < Ssz){
    float dtm = (i == 0) ? 0.f : (tsm[i] - tsm[i-1]);
    float de = (dtm > 1e-4f) ? dtm : 0.f;
    subs[i] = de * 0.125f;
  }
}

__global__ void dti_k(const float* tp, float* dti){
  int i = blockIdx.x*256 + threadIdx.x;
  int ss = i & 127;
  dti[i] = ss ? (tp[i] - tp[i-1]) : 0.f;
}

__global__ void tr1_k(const float* w1, unsigned short* w1t){
  int i = blockIdx.x*256 + threadIdx.x;
  int n = i >> 9, k = i & 511;
  w1t[i] = f2b(w1[(size_t)k*NTWO + n]);
}
__global__ void tr2_k(const float* w2, unsigned short* w2t){
  int i = blockIdx.x*256 + threadIdx.x;
  int n = i >> 10, k = i & 1023;
  w2t[i] = f2b(w2[(size_t)k*Hsz + n]);
}
__global__ void cvt_k(const float* src, unsigned short* dst, int n){
  int i = blockIdx.x*256 + threadIdx.x;
  if (i < n) dst[i] = f2b(src[i]);
}
__global__ void wix_k(const float* wih, unsigned short* wix){
  int i = blockIdx.x*256 + threadIdx.x;
  int n = i >> 7, k = i & 127;
  wix[i] = f2b(wih[(size_t)n*129 + k]);
}
__global__ void wdt_k(const float* wih, float* wdt){
  int i = blockIdx.x*256 + threadIdx.x;
  if (i < 1536) wdt[i] = wih[(size_t)i*129 + 128];
}
__global__ void u_k(const float* b2v, const unsigned short* w1t, float* u){
  int i = blockIdx.x*256 + threadIdx.x;
  if (i < NTWO){
    float acc = 0.f;
    for (int j = 0; j < Hsz; ++j) acc += b2v[j] * b2f(w1t[(size_t)i*Hsz + j]);
    u[i] = acc;
  }
}

__global__ void gru_ln_k(const float* __restrict__ GI, const float* __restrict__ GH,
                         float* __restrict__ h, unsigned short* __restrict__ h2,
                         const float* __restrict__ gamma,
                         const float* __restrict__ beta,
                         float* __restrict__ out_s){
  int b = blockIdx.x, tid = threadIdx.x;
  __shared__ float red[16];
  float hn[2];
  int gb = b*1536;
  #pragma unroll
  for (int i = 0; i < 2; ++i){
    int j = tid + i*256;
    float gr = GI[gb + j]        + GH[gb + j];
    float gz = GI[gb + 512 + j]  + GH[gb + 512 + j];
    float gnn = GI[gb + 1024 + j];
    float ghn = GH[gb + 1024 + j];
    float rg = 1.f/(1.f + __expf(-gr));
    float zg = 1.f/(1.f + __expf(-gz));
    float ng = tanhf(gnn + rg*ghn);
    float hv = h[b*Hsz + j];
    float vv = (1.f - zg)*ng + zg*hv;
    hn[i] = vv;
    h[b*Hsz + j] = vv;
    unsigned short hi = f2b(vv);
    h2[b*NTWO + j] = hi;
    h2[b*NTWO + Hsz + j] = f2b(vv - b2f(hi));
  }
  int wave = tid >> 6, lane = tid & 63;
  float sm = hn[0] + hn[1];
  for (int o = 32; o; o >>= 1) sm += __shfl_down(sm, o);
  if (!lane) red[wave] = sm;
  __syncthreads();
  if (!tid) red[8] = (red[0] + red[1] + red[2] + red[3]) * (1.f/512.f);
  __syncthreads();
  float mu = red[8];
  float d0 = hn[0] - mu, d1 = hn[1] - mu;
  float ss = d0*d0 + d1*d1;
  for (int o = 32; o; o >>= 1) ss += __shfl_down(ss, o);
  if (!lane) red[wave] = ss;
  __syncthreads();
  if (!tid) red[9] = sqrtf((red[0] + red[1] + red[2] + red[3]) * (1.f/512.f) + 1e-5f);
  __syncthreads();
  float sd = red[9];
  #pragma unroll
  for (int i = 0; i < 2; ++i){
    int j = tid + i*256;
    out_s[(size_t)b*(Ssz*Hsz) + j] = (hn[i] - mu)/sd * gamma[j] + beta[j];
  }
}

extern "C" void kernel_launch(void* const* d_in, const int* in_sizes, int n_in,
                              void* d_out, int out_size, void* d_ws, size_t ws_size,
                              hipStream_t stream){
  (void)in_sizes; (void)n_in; (void)out_size; (void)ws_size;
  const float* tp    = (const float*)d_in[0];
  const float* vals  = (const float*)d_in[1];
  const float* w1    = (const float*)d_in[2];
  const float* b1v   = (const float*)d_in[3];
  const float* w2    = (const float*)d_in[4];
  const float* b2v   = (const float*)d_in[5];
  const float* wih   = (const float*)d_in[6];
  const float* whh   = (const float*)d_in[7];
  const float* bih   = (const float*)d_in[8];
  const float* bhh   = (const float*)d_in[9];
  const float* gamma = (const float*)d_in[10];
  const float* beta  = (const float*)d_in[11];
  float* out = (float*)d_out;

  uint8_t* w = (uint8_t*)d_ws;
  size_t off = 0;
  auto alloc = [&](size_t bytes)->void*{
    void* pp = w + off; off += (bytes + 255) & ~(size_t)255; return pp; };
  float*          h      = (float*)alloc((size_t)Bsz*Hsz*4);
  unsigned short* h2     = (unsigned short*)alloc((size_t)Bsz*NTWO*2);
  float*          p      = (float*)alloc((size_t)Bsz*NTWO*4);
  unsigned short* t      = (unsigned short*)alloc((size_t)Bsz*NTWO*2);
  unsigned short* q0     = (unsigned short*)alloc((size_t)Bsz*NTWO*2);
  unsigned short* q1     = (unsigned short*)alloc((size_t)Bsz*NTWO*2);
  unsigned short* q2     = (unsigned short*)alloc((size_t)Bsz*NTWO*2);
  unsigned short* q3     = (unsigned short*)alloc((size_t)Bsz*NTWO*2);
  unsigned short* q4     = (unsigned short*)alloc((size_t)Bsz*NTWO*2);
  float*          Tacc   = (float*)alloc((size_t)Bsz*NTWO*4);
  unsigned short* Tbf    = (unsigned short*)alloc((size_t)Bsz*NTWO*2);
  float*          GHbuf  = (float*)alloc((size_t)Bsz*1536*4);
  float*          GIbuf  = (float*)alloc((size_t)Bsz*1536*4);
  unsigned short* Gt     = (unsigned short*)alloc((size_t)NTWO*NTWO*2);
  unsigned short* w1t    = (unsigned short*)alloc((size_t)NTWO*Hsz*2);
  unsigned short* w2t    = (unsigned short*)alloc((size_t)Hsz*NTWO*2);
  unsigned short* w2bf   = (unsigned short*)alloc((size_t)NTWO*Hsz*2);
  unsigned short* whhbf  = (unsigned short*)alloc((size_t)1536*Hsz*2);
  unsigned short* wix    = (unsigned short*)alloc((size_t)1536*128*2);
  unsigned short* valsbf = (unsigned short*)alloc((size_t)Bsz*Ssz*Fsz*2);
  float*          wdt    = (float*)alloc(1536*4);
  float*          uvec   = (float*)alloc(NTWO*4);
  float*          tsm    = (float*)alloc(Ssz*4);
  float*          subs   = (float*)alloc(Ssz*4);
  float*          dti    = (float*)alloc((size_t)Bsz*Ssz*4);

  hipLaunchKernelGGL(zero_k, dim3(2048), dim3(256), 0, stream, h, h2);
  hipLaunchKernelGGL(tsm_k,  dim3(128),  dim3(256), 0, stream, tp, tsm);
  hipLaunchKernelGGL(sub_k,  dim3(1),    dim3(128), 0, stream, tsm, subs);
  hipLaunchKernelGGL(dti_k,  dim3(256),  dim3(256), 0, stream, tp, dti);
  hipLaunchKernelGGL(tr1_k,  dim3(2048), dim3(256), 0, stream, w1, w1t);
  hipLaunchKernelGGL(tr2_k,  dim3(2048), dim3(256), 0, stream, w2, w2t);
  hipLaunchKernelGGL(cvt_k,  dim3(2048), dim3(256), 0, stream, w2, w2bf, NTWO*Hsz);
  hipLaunchKernelGGL(cvt_k,  dim3(3072), dim3(256), 0, stream, whh, whhbf, 1536*Hsz);
  hipLaunchKernelGGL(wix_k,  dim3(768),  dim3(256), 0, stream, wih, wix);
  hipLaunchKernelGGL(wdt_k,  dim3(6),    dim3(256), 0, stream, wih, wdt);
  hipLaunchKernelGGL(cvt_k,  dim3(32768),dim3(256), 0, stream, vals, valsbf, Bsz*Ssz*Fsz);
  hipLaunchKernelGGL(u_k,    dim3(4),    dim3(256), 0, stream, b2v, w1t, uvec);
  { // Gt[m][n] = G[n][m], G = w2@w1 : A = w1t (1024x512), Bt = w2bf (1024x512)
    GArgs g{}; g.A = w1t; g.Bt = w2bf; g.a_rs = Hsz; g.b_rs = Hsz; g.K = Hsz;
    g.kmask = 511; g.N = NTWO; g.mode = 5; g.GtOut = Gt;
    hipLaunchKernelGGL(gemm_k, dim3(16,32), dim3(256), 0, stream, g);
  }

  for (int s = 0; s < Ssz; ++s){
    const float* sp = subs + s;
    { // p = h@w1 + b1 (h as bf16 hi/lo, K doubled)
      GArgs g{}; g.A = h2; g.Bt = w1t; g.a_rs = NTWO; g.b_rs = Hsz; g.K = NTWO;
      g.kmask = 511; g.N = NTWO; g.mode = 1; g.subp = sp; g.bias = b1v;
      g.p = p; g.t = t; g.Tacc = Tacc;
      hipLaunchKernelGGL(gemm_k, dim3(8,32), dim3(256), 0, stream, g);
    }
    for (int ssb = 0; ssb < 8; ++ssb){
      for (int st = 1; st <= 6; ++st){
        if (ssb == 7 && st == 6) continue;  // last substep needs no p-update
        GArgs g{}; g.A = t; g.Bt = Gt; g.a_rs = NTWO; g.b_rs = NTWO; g.K = NTWO;
        g.kmask = 1023; g.N = NTWO; g.mode = 0; g.stage = st;
        g.wtbf = (ssb == 7 && st == 5) ? 1 : 0;
        g.subp = sp; g.u = uvec; g.p = p; g.t = t;
        g.q0 = q0; g.q1 = q1; g.q2 = q2; g.q3 = q3; g.q4 = q4;
        g.Tacc = Tacc; g.Tbf = Tbf;
        hipLaunchKernelGGL(gemm_k, dim3(8,32), dim3(256), 0, stream, g);
      }
    }
    { // h += Tacc@w2 + dt_eff*b2
      GArgs g{}; g.A = Tbf; g.Bt = w2t; g.a_rs = NTWO; g.b_rs = NTWO; g.K = NTWO;
      g.kmask = 1023; g.N = Hsz; g.mode = 2; g.subp = sp; g.bias = b2v;
      g.h = h; g.h2 = h2;
      hipLaunchKernelGGL(gemm_k, dim3(8,16), dim3(256), 0, stream, g);
    }
    { // GH = h@w_hh^T + b_hh
      GArgs g{}; g.A = h2; g.Bt = whhbf; g.a_rs = NTWO; g.b_rs = Hsz; g.K = NTWO;
      g.kmask = 511; g.N = 1536; g.mode = 3; g.bias = bhh; g.GO = GHbuf;
      hipLaunchKernelGGL(gemm_k, dim3(8,48), dim3(256), 0, stream, g);
    }
    { // GI = x_s@w_ih_x^T + dti*wdt + b_ih
      GArgs g{}; g.A = valsbf + (size_t)s*Fsz; g.Bt = wix; g.a_rs = Ssz*Fsz; g.b_rs = Fsz;
      g.K = Fsz; g.kmask = 127; g.N = 1536; g.mode = 4; g.bias = bih;
      g.GO = GIbuf; g.dti = dti + s; g.wdt = wdt;
      hipLaunchKernelGGL(gemm_k, dim3(8,48), dim3(256), 0, stream, g);
    }
    hipLaunchKernelGGL(gru_ln_k, dim3(512), dim3(256), 0, stream,
                       GIbuf, GHbuf, h, h2, gamma, beta, out + (size_t)s*Hsz);
  }
}